// Round 2
// baseline (812.692 us; speedup 1.0000x reference)
//
#include <hip/hip_runtime.h>
#include <math.h>

#define N_NODES 50000
#define N_EDGES 800000
#define ET (N_EDGES + N_NODES)   // edges + self loops
#define FDIM 512                 // HEADS*OUT_CH
#define NEG_SLOPE 0.2f
#define NBLK 196                 // ceil(50000/256)

// ---------------------------------------------------------------------------
// Detect whether edge_index is stored as int64 (lo,hi pairs) or int32.
__global__ void detect_i64_kernel(const int* __restrict__ ei, int* __restrict__ flag) {
    __shared__ int bad_sh[256];
    int t = threadIdx.x;
    int bad = 0;
    for (int i = t; i < 1024; i += 256)
        if (ei[2 * i + 1] != 0) bad = 1;
    bad_sh[t] = bad;
    __syncthreads();
    for (int s = 128; s > 0; s >>= 1) {
        if (t < s) bad_sh[t] |= bad_sh[t + s];
        __syncthreads();
    }
    if (t == 0) *flag = bad_sh[0] ? 0 : 1;   // 1 => int64 layout
}

__device__ __forceinline__ int load_src(const int* ei, int is64, int e) {
    if (e < N_EDGES) return is64 ? ei[2 * e] : ei[e];
    return e - N_EDGES;                       // self loop
}
__device__ __forceinline__ int load_dst(const int* ei, int is64, int e) {
    if (e < N_EDGES) return is64 ? ei[2 * (N_EDGES + e)] : ei[N_EDGES + e];
    return e - N_EDGES;                       // self loop
}

// ---------------------------------------------------------------------------
__global__ void count_deg_kernel(const int* __restrict__ ei, const int* __restrict__ flag,
                                 int* __restrict__ deg) {
    int is64 = *flag;
    for (int e = blockIdx.x * blockDim.x + threadIdx.x; e < ET; e += gridDim.x * blockDim.x) {
        int dst = load_dst(ei, is64, e);
        atomicAdd(&deg[dst], 1);
    }
}

// --- coalesced 3-stage scan ------------------------------------------------
__global__ void deg_block_sum_kernel(const int* __restrict__ deg, int* __restrict__ bsum) {
    __shared__ int s[256];
    int t = threadIdx.x;
    int i = blockIdx.x * 256 + t;
    s[t] = (i < N_NODES) ? deg[i] : 0;
    __syncthreads();
    for (int off = 128; off > 0; off >>= 1) {
        if (t < off) s[t] += s[t + off];
        __syncthreads();
    }
    if (t == 0) bsum[blockIdx.x] = s[0];
}

__global__ void scan_bsums_kernel(const int* __restrict__ bsum, int* __restrict__ boff) {
    __shared__ int s[256];
    int t = threadIdx.x;
    int v = (t < NBLK) ? bsum[t] : 0;
    s[t] = v;
    __syncthreads();
    for (int off = 1; off < 256; off <<= 1) {
        int u = 0;
        if (t >= off) u = s[t - off];
        __syncthreads();
        if (t >= off) s[t] += u;
        __syncthreads();
    }
    if (t < NBLK) boff[t] = s[t] - v;   // exclusive
}

__global__ void scan_apply_kernel(const int* __restrict__ deg, const int* __restrict__ boff,
                                  int* __restrict__ row_start, int* __restrict__ cursor) {
    __shared__ int s[256];
    int t = threadIdx.x;
    int i = blockIdx.x * 256 + t;
    int v = (i < N_NODES) ? deg[i] : 0;
    s[t] = v;
    __syncthreads();
    for (int off = 1; off < 256; off <<= 1) {
        int u = 0;
        if (t >= off) u = s[t - off];
        __syncthreads();
        if (t >= off) s[t] += u;
        __syncthreads();
    }
    int excl = s[t] - v + boff[blockIdx.x];
    if (i < N_NODES) {
        row_start[i] = excl;
        cursor[i]    = excl;
        if (i == N_NODES - 1) row_start[N_NODES] = excl + v;
    }
}

__global__ void fill_csr_kernel(const int* __restrict__ ei, const int* __restrict__ flag,
                                int* __restrict__ cursor, int* __restrict__ csr_src) {
    int is64 = *flag;
    for (int e = blockIdx.x * blockDim.x + threadIdx.x; e < ET; e += gridDim.x * blockDim.x) {
        int src = load_src(ei, is64, e);
        int dst = load_dst(ei, is64, e);
        int pos = atomicAdd(&cursor[dst], 1);
        csr_src[pos] = src;
    }
}

// ---------------------------------------------------------------------------
// One wave per destination node, 8 waves (512 threads) per block.
// x_l[src] is RECOMPUTED per edge from feat[src] (L2-resident, 64 B/edge)
// times W_l held in 128 VGPRs per lane -> no 2 KB/edge gather, VALU-bound.
// Lane l owns flat channels [8l, 8l+8): lanes [16h,16h+16) cover head h.
__global__ __launch_bounds__(512, 2) void gat_aggregate_kernel(
        const float* __restrict__ feat, const float* __restrict__ Wl,
        const float* __restrict__ Wr,   const float* __restrict__ att,
        const float* __restrict__ bias, const int* __restrict__ row_start,
        const int* __restrict__ csr_src, float* __restrict__ out) {
    __shared__ float wr_sh[16 * FDIM];   // 32 KB
    __shared__ float att_sh[FDIM];
    __shared__ float bias_sh[FDIM];

    int t = threadIdx.x;
    for (int i = t; i < 16 * FDIM / 4; i += 512)
        ((float4*)wr_sh)[i] = ((const float4*)Wr)[i];
    if (t < FDIM / 4)        ((float4*)att_sh)[t]        = ((const float4*)att)[t];
    else if (t < FDIM / 2)   ((float4*)bias_sh)[t - 128] = ((const float4*)bias)[t - 128];
    __syncthreads();

    int wave = t >> 6, lane = t & 63;
    int node = blockIdx.x * 8 + wave;    // grid*8 == N_NODES exactly
    int cbase = lane * 8;

    // W_l columns for this lane's 8 channels -> registers (reused every edge)
    float wl[16][8];
#pragma unroll
    for (int k = 0; k < 16; k++) {
        float4 wa = *(const float4*)(Wl + k * FDIM + cbase);
        float4 wb = *(const float4*)(Wl + k * FDIM + cbase + 4);
        wl[k][0] = wa.x; wl[k][1] = wa.y; wl[k][2] = wa.z; wl[k][3] = wa.w;
        wl[k][4] = wb.x; wl[k][5] = wb.y; wl[k][6] = wb.z; wl[k][7] = wb.w;
    }

    // feat[node] (broadcast) -> x_r for this lane's channels
    float f[16];
    {
        const float4* fp = (const float4*)(feat + (size_t)node * 16);
        float4 f0 = fp[0], f1 = fp[1], f2 = fp[2], f3 = fp[3];
        f[0]=f0.x; f[1]=f0.y; f[2]=f0.z; f[3]=f0.w;
        f[4]=f1.x; f[5]=f1.y; f[6]=f1.z; f[7]=f1.w;
        f[8]=f2.x; f[9]=f2.y; f[10]=f2.z; f[11]=f2.w;
        f[12]=f3.x; f[13]=f3.y; f[14]=f3.z; f[15]=f3.w;
    }
    float xr[8];
#pragma unroll
    for (int j = 0; j < 8; j++) xr[j] = 0.f;
#pragma unroll
    for (int k = 0; k < 16; k++) {
        float fk = f[k];
        float4 wa = *(const float4*)(wr_sh + k * FDIM + cbase);
        float4 wb = *(const float4*)(wr_sh + k * FDIM + cbase + 4);
        xr[0] = fmaf(fk, wa.x, xr[0]); xr[1] = fmaf(fk, wa.y, xr[1]);
        xr[2] = fmaf(fk, wa.z, xr[2]); xr[3] = fmaf(fk, wa.w, xr[3]);
        xr[4] = fmaf(fk, wb.x, xr[4]); xr[5] = fmaf(fk, wb.y, xr[5]);
        xr[6] = fmaf(fk, wb.z, xr[6]); xr[7] = fmaf(fk, wb.w, xr[7]);
    }

    float a[8];
    {
        float4 a0 = *(const float4*)(att_sh + cbase);
        float4 a1 = *(const float4*)(att_sh + cbase + 4);
        a[0]=a0.x; a[1]=a0.y; a[2]=a0.z; a[3]=a0.w;
        a[4]=a1.x; a[5]=a1.y; a[6]=a1.z; a[7]=a1.w;
    }

    float m = -INFINITY, d = 0.f;
    float acc[8];
#pragma unroll
    for (int j = 0; j < 8; j++) acc[j] = 0.f;

    int e0 = row_start[node], e1 = row_start[node + 1];

    // prefetch first edge's feat row (every node has >=1 edge: self loop)
    float4 g0, g1, g2, g3;
    {
        int src = csr_src[e0];
        const float4* gp = (const float4*)(feat + (size_t)src * 16);
        g0 = gp[0]; g1 = gp[1]; g2 = gp[2]; g3 = gp[3];
    }

    for (int k = e0; k < e1; k++) {
        float fx[16];
        fx[0]=g0.x; fx[1]=g0.y; fx[2]=g0.z; fx[3]=g0.w;
        fx[4]=g1.x; fx[5]=g1.y; fx[6]=g1.z; fx[7]=g1.w;
        fx[8]=g2.x; fx[9]=g2.y; fx[10]=g2.z; fx[11]=g2.w;
        fx[12]=g3.x; fx[13]=g3.y; fx[14]=g3.z; fx[15]=g3.w;

        if (k + 1 < e1) {   // prefetch next edge
            int s2 = csr_src[k + 1];
            const float4* gp = (const float4*)(feat + (size_t)s2 * 16);
            g0 = gp[0]; g1 = gp[1]; g2 = gp[2]; g3 = gp[3];
        }

        // recompute x_l[src] for this lane's 8 channels
        float xv[8];
#pragma unroll
        for (int j = 0; j < 8; j++) xv[j] = fx[0] * wl[0][j];
#pragma unroll
        for (int kk = 1; kk < 16; kk++)
#pragma unroll
            for (int j = 0; j < 8; j++) xv[j] = fmaf(fx[kk], wl[kk][j], xv[j]);

        float p = 0.f;
#pragma unroll
        for (int j = 0; j < 8; j++) {
            float s = xv[j] + xr[j];
            float lr = s > 0.f ? s : NEG_SLOPE * s;
            p = fmaf(lr, a[j], p);
        }
        // reduce over the 16 lanes of this head
        p += __shfl_xor(p, 1);
        p += __shfl_xor(p, 2);
        p += __shfl_xor(p, 4);
        p += __shfl_xor(p, 8);

        float nm = fmaxf(m, p);
        float scale = __expf(m - nm);    // first iter: exp(-inf)=0
        float w = __expf(p - nm);
        d = d * scale + w;
#pragma unroll
        for (int j = 0; j < 8; j++) acc[j] = fmaf(acc[j], scale, w * xv[j]);
        m = nm;
    }

    float inv = 1.f / (d + 1e-16f);
    float o[8];
#pragma unroll
    for (int j = 0; j < 8; j++) o[j] = fmaf(acc[j], inv, bias_sh[cbase + j]);
    float* op = out + (size_t)node * FDIM + cbase;
    *(float4*)op       = make_float4(o[0], o[1], o[2], o[3]);
    *(float4*)(op + 4) = make_float4(o[4], o[5], o[6], o[7]);
}

// ---------------------------------------------------------------------------
extern "C" void kernel_launch(void* const* d_in, const int* in_sizes, int n_in,
                              void* d_out, int out_size, void* d_ws, size_t ws_size,
                              hipStream_t stream) {
    const float* feat = (const float*)d_in[0];
    const int*   ei   = (const int*)d_in[1];
    const float* Wl   = (const float*)d_in[2];
    const float* Wr   = (const float*)d_in[3];
    const float* att  = (const float*)d_in[4];
    const float* bias = (const float*)d_in[5];
    float* out = (float*)d_out;

    char* ws = (char*)d_ws;
    size_t off = 0;
    int* row_start = (int*)(ws + off); off += (size_t)(N_NODES + 1) * sizeof(int);
    int* cursor    = (int*)(ws + off); off += (size_t)N_NODES * sizeof(int);
    int* deg       = (int*)(ws + off); off += (size_t)N_NODES * sizeof(int);
    int* csr_src   = (int*)(ws + off); off += (size_t)ET * sizeof(int);
    int* bsum      = (int*)(ws + off); off += (size_t)NBLK * sizeof(int);
    int* boff      = (int*)(ws + off); off += (size_t)NBLK * sizeof(int);
    int* flag      = (int*)(ws + off); off += sizeof(int);
    (void)ws_size; (void)in_sizes; (void)n_in; (void)out_size;

    hipMemsetAsync(deg, 0, (size_t)N_NODES * sizeof(int), stream);
    detect_i64_kernel<<<1, 256, 0, stream>>>(ei, flag);
    count_deg_kernel<<<512, 256, 0, stream>>>(ei, flag, deg);
    deg_block_sum_kernel<<<NBLK, 256, 0, stream>>>(deg, bsum);
    scan_bsums_kernel<<<1, 256, 0, stream>>>(bsum, boff);
    scan_apply_kernel<<<NBLK, 256, 0, stream>>>(deg, boff, row_start, cursor);
    fill_csr_kernel<<<512, 256, 0, stream>>>(ei, flag, cursor, csr_src);
    gat_aggregate_kernel<<<N_NODES / 8, 512, 0, stream>>>(
        feat, Wl, Wr, att, bias, row_start, csr_src, out);
}

// Round 3
// 425.622 us; speedup vs baseline: 1.9094x; 1.9094x over previous
//
#include <hip/hip_runtime.h>
#include <math.h>

#define N_NODES 50000
#define N_EDGES 800000
#define ET (N_EDGES + N_NODES)   // edges + self loops
#define FDIM 512                 // HEADS*OUT_CH
#define NEG_SLOPE 0.2f
#define NBLK 196                 // ceil(50000/256)

// ---------------------------------------------------------------------------
// Detect whether edge_index is stored as int64 (lo,hi pairs) or int32.
__global__ void detect_i64_kernel(const int* __restrict__ ei, int* __restrict__ flag) {
    __shared__ int bad_sh[256];
    int t = threadIdx.x;
    int bad = 0;
    for (int i = t; i < 1024; i += 256)
        if (ei[2 * i + 1] != 0) bad = 1;
    bad_sh[t] = bad;
    __syncthreads();
    for (int s = 128; s > 0; s >>= 1) {
        if (t < s) bad_sh[t] |= bad_sh[t + s];
        __syncthreads();
    }
    if (t == 0) *flag = bad_sh[0] ? 0 : 1;   // 1 => int64 layout
}

__device__ __forceinline__ int load_src(const int* ei, int is64, int e) {
    if (e < N_EDGES) return is64 ? ei[2 * e] : ei[e];
    return e - N_EDGES;                       // self loop
}
__device__ __forceinline__ int load_dst(const int* ei, int is64, int e) {
    if (e < N_EDGES) return is64 ? ei[2 * (N_EDGES + e)] : ei[N_EDGES + e];
    return e - N_EDGES;                       // self loop
}

// ---------------------------------------------------------------------------
__global__ void count_deg_kernel(const int* __restrict__ ei, const int* __restrict__ flag,
                                 int* __restrict__ deg) {
    int is64 = *flag;
    for (int e = blockIdx.x * blockDim.x + threadIdx.x; e < ET; e += gridDim.x * blockDim.x) {
        int dst = load_dst(ei, is64, e);
        atomicAdd(&deg[dst], 1);
    }
}

// --- coalesced 3-stage scan ------------------------------------------------
__global__ void deg_block_sum_kernel(const int* __restrict__ deg, int* __restrict__ bsum) {
    __shared__ int s[256];
    int t = threadIdx.x;
    int i = blockIdx.x * 256 + t;
    s[t] = (i < N_NODES) ? deg[i] : 0;
    __syncthreads();
    for (int off = 128; off > 0; off >>= 1) {
        if (t < off) s[t] += s[t + off];
        __syncthreads();
    }
    if (t == 0) bsum[blockIdx.x] = s[0];
}

__global__ void scan_bsums_kernel(const int* __restrict__ bsum, int* __restrict__ boff) {
    __shared__ int s[256];
    int t = threadIdx.x;
    int v = (t < NBLK) ? bsum[t] : 0;
    s[t] = v;
    __syncthreads();
    for (int off = 1; off < 256; off <<= 1) {
        int u = 0;
        if (t >= off) u = s[t - off];
        __syncthreads();
        if (t >= off) s[t] += u;
        __syncthreads();
    }
    if (t < NBLK) boff[t] = s[t] - v;   // exclusive
}

__global__ void scan_apply_kernel(const int* __restrict__ deg, const int* __restrict__ boff,
                                  int* __restrict__ row_start, int* __restrict__ cursor) {
    __shared__ int s[256];
    int t = threadIdx.x;
    int i = blockIdx.x * 256 + t;
    int v = (i < N_NODES) ? deg[i] : 0;
    s[t] = v;
    __syncthreads();
    for (int off = 1; off < 256; off <<= 1) {
        int u = 0;
        if (t >= off) u = s[t - off];
        __syncthreads();
        if (t >= off) s[t] += u;
        __syncthreads();
    }
    int excl = s[t] - v + boff[blockIdx.x];
    if (i < N_NODES) {
        row_start[i] = excl;
        cursor[i]    = excl;
        if (i == N_NODES - 1) row_start[N_NODES] = excl + v;
    }
}

__global__ void fill_csr_kernel(const int* __restrict__ ei, const int* __restrict__ flag,
                                int* __restrict__ cursor, int* __restrict__ csr_src) {
    int is64 = *flag;
    for (int e = blockIdx.x * blockDim.x + threadIdx.x; e < ET; e += gridDim.x * blockDim.x) {
        int src = load_src(ei, is64, e);
        int dst = load_dst(ei, is64, e);
        int pos = atomicAdd(&cursor[dst], 1);
        csr_src[pos] = src;
    }
}

// ---------------------------------------------------------------------------
__device__ __forceinline__ unsigned short f2bf(float x) {
    unsigned int u = __float_as_uint(x);
    u = (u + 0x7FFFu + ((u >> 16) & 1u)) >> 16;   // round-to-nearest-even
    return (unsigned short)u;
}

// x_l = feat @ W_l, stored bf16-packed (2 ch per uint). 64 nodes per block.
__global__ __launch_bounds__(256) void gemm_xl_kernel(const float* __restrict__ feat,
                                                      const float* __restrict__ Wl,
                                                      unsigned int* __restrict__ xlb) {
    __shared__ float fsh[64 * 16];
    int t = threadIdx.x;
    int node0 = blockIdx.x * 64;
    int nvalid = min(64, N_NODES - node0);

    float w0[16], w1[16];
#pragma unroll
    for (int k = 0; k < 16; k++) {
        float2 w = ((const float2*)(Wl + k * FDIM))[t];
        w0[k] = w.x; w1[k] = w.y;
    }
    if (t < nvalid * 4) {
        ((float4*)fsh)[t] = ((const float4*)(feat + (size_t)node0 * 16))[t];
    }
    __syncthreads();

    for (int n = 0; n < nvalid; n++) {
        float a0 = 0.f, a1 = 0.f;
#pragma unroll
        for (int k = 0; k < 16; k++) {
            float f = fsh[n * 16 + k];
            a0 = fmaf(f, w0[k], a0);
            a1 = fmaf(f, w1[k], a1);
        }
        xlb[(size_t)(node0 + n) * 256 + t] =
            (unsigned int)f2bf(a0) | ((unsigned int)f2bf(a1) << 16);
    }
}

// ---------------------------------------------------------------------------
// DPP rotate-add within each 16-lane row (one head): cheap all-reduce.
#define DPP_ROR_ADD(x, ctrl) \
    ((x) + __int_as_float(__builtin_amdgcn_update_dpp(0, __float_as_int(x), (ctrl), 0xF, 0xF, true)))

__device__ __forceinline__ void unpack8(uint4 u, float* xv) {
    xv[0] = __uint_as_float(u.x << 16); xv[1] = __uint_as_float(u.x & 0xFFFF0000u);
    xv[2] = __uint_as_float(u.y << 16); xv[3] = __uint_as_float(u.y & 0xFFFF0000u);
    xv[4] = __uint_as_float(u.z << 16); xv[5] = __uint_as_float(u.z & 0xFFFF0000u);
    xv[6] = __uint_as_float(u.w << 16); xv[7] = __uint_as_float(u.w & 0xFFFF0000u);
}

__device__ __forceinline__ float partial_score(const float* xv, const float* xr, const float* a) {
    float p = 0.f;
#pragma unroll
    for (int j = 0; j < 8; j++) {
        float s = xv[j] + xr[j];
        float lr = s > 0.f ? s : NEG_SLOPE * s;
        p = fmaf(lr, a[j], p);
    }
    return p;
}

// One wave per destination node, 8 waves per block, NO LDS.
// Edges processed in batches of 4: 4 gathers in flight, one softmax merge.
__global__ __launch_bounds__(512) void gat_aggregate_kernel(
        const float* __restrict__ feat, const float* __restrict__ Wr,
        const float* __restrict__ att,  const float* __restrict__ bias,
        const uint4* __restrict__ xlb,  const int* __restrict__ row_start,
        const int* __restrict__ csr_src, float* __restrict__ out) {
    int t = threadIdx.x;
    int wave = t >> 6, lane = t & 63;
    int node = blockIdx.x * 8 + wave;    // grid*8 == N_NODES exactly
    int cbase = lane * 8;

    // feat[node] broadcast
    float f[16];
    {
        const float4* fp = (const float4*)(feat + (size_t)node * 16);
        float4 f0 = fp[0], f1 = fp[1], f2 = fp[2], f3 = fp[3];
        f[0]=f0.x; f[1]=f0.y; f[2]=f0.z; f[3]=f0.w;
        f[4]=f1.x; f[5]=f1.y; f[6]=f1.z; f[7]=f1.w;
        f[8]=f2.x; f[9]=f2.y; f[10]=f2.z; f[11]=f2.w;
        f[12]=f3.x; f[13]=f3.y; f[14]=f3.z; f[15]=f3.w;
    }

    // x_r[node] for this lane's 8 channels (W_r read from global; L1-resident)
    float xr[8];
#pragma unroll
    for (int j = 0; j < 8; j++) xr[j] = 0.f;
#pragma unroll
    for (int k = 0; k < 16; k++) {
        float fk = f[k];
        float4 wa = *(const float4*)(Wr + k * FDIM + cbase);
        float4 wb = *(const float4*)(Wr + k * FDIM + cbase + 4);
        xr[0] = fmaf(fk, wa.x, xr[0]); xr[1] = fmaf(fk, wa.y, xr[1]);
        xr[2] = fmaf(fk, wa.z, xr[2]); xr[3] = fmaf(fk, wa.w, xr[3]);
        xr[4] = fmaf(fk, wb.x, xr[4]); xr[5] = fmaf(fk, wb.y, xr[5]);
        xr[6] = fmaf(fk, wb.z, xr[6]); xr[7] = fmaf(fk, wb.w, xr[7]);
    }

    float a[8];
    {
        float4 a0 = *(const float4*)(att + cbase);
        float4 a1 = *(const float4*)(att + cbase + 4);
        a[0]=a0.x; a[1]=a0.y; a[2]=a0.z; a[3]=a0.w;
        a[4]=a1.x; a[5]=a1.y; a[6]=a1.z; a[7]=a1.w;
    }

    float m = -INFINITY, d = 0.f;
    float acc[8];
#pragma unroll
    for (int j = 0; j < 8; j++) acc[j] = 0.f;

    int e0 = row_start[node], e1 = row_start[node + 1];

    for (int k = e0; k < e1; k += 4) {
        int r = e1 - k;
        int s0 = csr_src[k];
        int s1 = (r > 1) ? csr_src[k + 1] : s0;
        int s2 = (r > 2) ? csr_src[k + 2] : s0;
        int s3 = (r > 3) ? csr_src[k + 3] : s0;

        // 4 independent 16B gathers in flight
        uint4 u0 = xlb[(size_t)s0 * 64 + lane];
        uint4 u1 = xlb[(size_t)s1 * 64 + lane];
        uint4 u2 = xlb[(size_t)s2 * 64 + lane];
        uint4 u3 = xlb[(size_t)s3 * 64 + lane];

        float x0[8], x1[8], x2[8], x3[8];
        unpack8(u0, x0); unpack8(u1, x1); unpack8(u2, x2); unpack8(u3, x3);

        float p0 = partial_score(x0, xr, a);
        float p1 = partial_score(x1, xr, a);
        float p2 = partial_score(x2, xr, a);
        float p3 = partial_score(x3, xr, a);

        // interleaved DPP all-reduce within each 16-lane head group
        p0 = DPP_ROR_ADD(p0, 0x128); p1 = DPP_ROR_ADD(p1, 0x128);
        p2 = DPP_ROR_ADD(p2, 0x128); p3 = DPP_ROR_ADD(p3, 0x128);
        p0 = DPP_ROR_ADD(p0, 0x124); p1 = DPP_ROR_ADD(p1, 0x124);
        p2 = DPP_ROR_ADD(p2, 0x124); p3 = DPP_ROR_ADD(p3, 0x124);
        p0 = DPP_ROR_ADD(p0, 0x122); p1 = DPP_ROR_ADD(p1, 0x122);
        p2 = DPP_ROR_ADD(p2, 0x122); p3 = DPP_ROR_ADD(p3, 0x122);
        p0 = DPP_ROR_ADD(p0, 0x121); p1 = DPP_ROR_ADD(p1, 0x121);
        p2 = DPP_ROR_ADD(p2, 0x121); p3 = DPP_ROR_ADD(p3, 0x121);

        if (r < 2) p1 = -INFINITY;
        if (r < 3) p2 = -INFINITY;
        if (r < 4) p3 = -INFINITY;

        float nm = fmaxf(fmaxf(fmaxf(m, p0), fmaxf(p1, p2)), p3);
        float sc = __expf(m - nm);           // first batch: exp(-inf)=0
        float w0 = __expf(p0 - nm);
        float w1 = __expf(p1 - nm);
        float w2 = __expf(p2 - nm);
        float w3 = __expf(p3 - nm);
        d = fmaf(d, sc, (w0 + w1) + (w2 + w3));
#pragma unroll
        for (int j = 0; j < 8; j++) {
            float v = acc[j] * sc;
            v = fmaf(w0, x0[j], v);
            v = fmaf(w1, x1[j], v);
            v = fmaf(w2, x2[j], v);
            v = fmaf(w3, x3[j], v);
            acc[j] = v;
        }
        m = nm;
    }

    float inv = 1.f / (d + 1e-16f);
    float4 b0 = *(const float4*)(bias + cbase);
    float4 b1 = *(const float4*)(bias + cbase + 4);
    float bb[8] = {b0.x, b0.y, b0.z, b0.w, b1.x, b1.y, b1.z, b1.w};
    float o[8];
#pragma unroll
    for (int j = 0; j < 8; j++) o[j] = fmaf(acc[j], inv, bb[j]);
    float* op = out + (size_t)node * FDIM + cbase;
    *(float4*)op       = make_float4(o[0], o[1], o[2], o[3]);
    *(float4*)(op + 4) = make_float4(o[4], o[5], o[6], o[7]);
}

// ---------------------------------------------------------------------------
extern "C" void kernel_launch(void* const* d_in, const int* in_sizes, int n_in,
                              void* d_out, int out_size, void* d_ws, size_t ws_size,
                              hipStream_t stream) {
    const float* feat = (const float*)d_in[0];
    const int*   ei   = (const int*)d_in[1];
    const float* Wl   = (const float*)d_in[2];
    const float* Wr   = (const float*)d_in[3];
    const float* att  = (const float*)d_in[4];
    const float* bias = (const float*)d_in[5];
    float* out = (float*)d_out;

    char* ws = (char*)d_ws;
    size_t off = 0;
    unsigned int* xlb = (unsigned int*)(ws + off); off += (size_t)N_NODES * 256 * sizeof(unsigned int);
    int* row_start = (int*)(ws + off); off += (size_t)(N_NODES + 1) * sizeof(int);
    int* cursor    = (int*)(ws + off); off += (size_t)N_NODES * sizeof(int);
    int* deg       = (int*)(ws + off); off += (size_t)N_NODES * sizeof(int);
    int* csr_src   = (int*)(ws + off); off += (size_t)ET * sizeof(int);
    int* bsum      = (int*)(ws + off); off += (size_t)NBLK * sizeof(int);
    int* boff      = (int*)(ws + off); off += (size_t)NBLK * sizeof(int);
    int* flag      = (int*)(ws + off); off += sizeof(int);
    (void)ws_size; (void)in_sizes; (void)n_in; (void)out_size;

    hipMemsetAsync(deg, 0, (size_t)N_NODES * sizeof(int), stream);
    detect_i64_kernel<<<1, 256, 0, stream>>>(ei, flag);
    gemm_xl_kernel<<<(N_NODES + 63) / 64, 256, 0, stream>>>(feat, Wl, xlb);
    count_deg_kernel<<<512, 256, 0, stream>>>(ei, flag, deg);
    deg_block_sum_kernel<<<NBLK, 256, 0, stream>>>(deg, bsum);
    scan_bsums_kernel<<<1, 256, 0, stream>>>(bsum, boff);
    scan_apply_kernel<<<NBLK, 256, 0, stream>>>(deg, boff, row_start, cursor);
    fill_csr_kernel<<<512, 256, 0, stream>>>(ei, flag, cursor, csr_src);
    gat_aggregate_kernel<<<N_NODES / 8, 512, 0, stream>>>(
        feat, Wr, att, bias, (const uint4*)xlb, row_start, csr_src, out);
}